// Round 13
// baseline (309.157 us; speedup 1.0000x reference)
//
#include <hip/hip_runtime.h>
#include <hip/hip_bf16.h>

#define NB 16
#define VV 5000
#define NFD 352
#define KD 120
#define NCH 6
#define SLABSZ (352 * 120)

typedef __attribute__((ext_vector_type(8))) short short8;
typedef __attribute__((ext_vector_type(4))) float float4v;

__device__ __forceinline__ unsigned short bfb(float a) {
    return __builtin_bit_cast(unsigned short, __float2bfloat16(a));
}

// split fp32 -> bf16 hi + bf16 lo(residual), pack 8 of each into int4
__device__ __forceinline__ void pack8(const float* f, int4& hi, int4& lo) {
    unsigned short h[8], l[8];
    #pragma unroll
    for (int j = 0; j < 8; ++j) {
        const float a = f[j];
        const __hip_bfloat16 hb = __float2bfloat16(a);
        h[j] = __builtin_bit_cast(unsigned short, hb);
        l[j] = bfb(a - __bfloat162float(hb));
    }
    hi.x = h[0] | (h[1] << 16); hi.y = h[2] | (h[3] << 16);
    hi.z = h[4] | (h[5] << 16); hi.w = h[6] | (h[7] << 16);
    lo.x = l[0] | (l[1] << 16); lo.y = l[2] | (l[3] << 16);
    lo.z = l[4] | (l[5] << 16); lo.w = l[6] | (l[7] << 16);
}

// ---------------------------------------------------------------------------
// proj v7: F_hat[b,f,k] = sum_v feat[b,v,f]*evecs[b,v,k]
// v6b was latency/occupancy bound: no pipe >35% busy (LDS BW 21%, VALU 22%,
// MFMA 14%, HBM 15%); per-step vmcnt stall (~200-400cy) + 3.75 blocks/CU.
// v7 = v6b + (a) NCH 6 -> 1152 blocks ~ 4.5-5 blocks/CU (~18 waves, 55% occ)
//           + (b) P/Q staging sets with TWO-step load->use distance (loads
//             for st+2 issued at st; consumed at st+1's pack_write) -> vmcnt
//             stall ~ 0. Step counts padded even, live-flag zero-fills pad.
// LDS (unchanged): A_hi[64 x 80B]@0 | A_lo@5120 | B_hi[128 x 80B]@10240 |
// B_lo@20480 (30720 B). 80B rows: bank-quad = 5m mod 8, conflict-free.
// Tile 64x128, BK=32, 4 waves 2x2 (wave tile 32x64), acc 2x4.
// Chunks: ch<5: 864 v (27 live steps, padded 28), ch5: 680 v (22 steps,
// v<VV tail guard). grid (36,2,16) = 1152 = 8 x 144, bijective XCD swizzle.
// ---------------------------------------------------------------------------
__global__ __launch_bounds__(256, 4) void proj_mfma(
    const float* __restrict__ fx, const float* __restrict__ fy,
    const float* __restrict__ ex, const float* __restrict__ ey,
    float* __restrict__ partials)
{
    const int t = threadIdx.x;

    // bijective XCD swizzle: 1152 = 8 x 144
    int lin = blockIdx.x + 36 * (blockIdx.y + 2 * blockIdx.z);
    lin = (lin & 7) * 144 + (lin >> 3);
    const int xx   = lin % 36;
    const int rest = lin / 36;
    const int wh = rest & 1;
    const int b  = rest >> 1;
    const int mt = xx % 6;
    const int ch = xx / 6;

    const float* Ab = (wh ? fy : fx) + (size_t)b * VV * NFD;
    const float* Bb = (wh ? ey : ex) + (size_t)b * VV * KD;
    const int m0 = mt * 64;

    __shared__ __align__(16) unsigned char lds[30720];

    // ---- staging geometry ----
    const int am = t & 63;                   // A: 64 m x 4 octets
    const int ao = t >> 6;
    const float* aSrc = Ab + min(m0 + am, NFD - 1);
    const int awb = am * 80 + ao * 16;
    const int bn0 = t & 127;                 // B: 128 n x 4 octets (2 per thread)
    const int bo0 = (t >> 7) & 3;
    const int bo1 = ((256 + t) >> 7) & 3;
    const float* bSrc0 = Bb + min(bn0, KD - 1);
    const int bwb0 = bn0 * 80 + bo0 * 16;
    const int bwb1 = bn0 * 80 + bo1 * 16;

    // ---- wave geometry: 4 waves 2x2, wave tile 32(m) x 64(n) ----
    const int lane = t & 63;
    const int wid  = t >> 6;
    const int wm = wid >> 1, wn = wid & 1;
    const int r16 = lane & 15;
    const int g   = lane >> 4;

    int aoffs[2], boffs[4];
    #pragma unroll
    for (int mf = 0; mf < 2; ++mf)
        aoffs[mf] = (wm * 32 + mf * 16 + r16) * 80 + g * 16;
    #pragma unroll
    for (int nf = 0; nf < 4; ++nf)
        boffs[nf] = 10240 + (wn * 64 + nf * 16 + r16) * 80 + g * 16;

    float4v acc[2][4];
    #pragma unroll
    for (int mf = 0; mf < 2; ++mf)
        #pragma unroll
        for (int nf = 0; nf < 4; ++nf)
            acc[mf][nf] = float4v{0.f, 0.f, 0.f, 0.f};

    const int chv0 = ch * 864;
    const int nst  = (ch < 5) ? 28 : 22;     // even (27 live + 1 pad | 22 w/ guard)
    const int nlive = (ch < 5) ? 27 : 22;

    float a8P[8], b8aP[8], b8bP[8];
    float a8Q[8], b8aQ[8], b8bQ[8];

    auto load_regs = [&](int st, float (&a8)[8], float (&b8a)[8], float (&b8b)[8]) {
        if (st >= nlive) {                   // pad step: zero-fill, no loads
            #pragma unroll
            for (int j = 0; j < 8; ++j) { a8[j] = 0.f; b8a[j] = 0.f; b8b[j] = 0.f; }
            return;
        }
        const int v0 = chv0 + st * 32;
        const int va  = v0 + ao * 8;
        const int vb0 = v0 + bo0 * 8;
        const int vb1 = v0 + bo1 * 8;
        if (v0 + 32 <= VV) {
            #pragma unroll
            for (int j = 0; j < 8; ++j) a8[j]  = aSrc [(size_t)(va  + j) * NFD];
            #pragma unroll
            for (int j = 0; j < 8; ++j) b8a[j] = bSrc0[(size_t)(vb0 + j) * KD];
            #pragma unroll
            for (int j = 0; j < 8; ++j) b8b[j] = bSrc0[(size_t)(vb1 + j) * KD];
        } else {
            #pragma unroll
            for (int j = 0; j < 8; ++j) {
                float v = 0.f;
                if (va + j < VV) v = aSrc[(size_t)(va + j) * NFD];
                a8[j] = v;
            }
            #pragma unroll
            for (int j = 0; j < 8; ++j) {
                float v = 0.f;
                if (vb0 + j < VV) v = bSrc0[(size_t)(vb0 + j) * KD];
                b8a[j] = v;
            }
            #pragma unroll
            for (int j = 0; j < 8; ++j) {
                float v = 0.f;
                if (vb1 + j < VV) v = bSrc0[(size_t)(vb1 + j) * KD];
                b8b[j] = v;
            }
        }
    };

    auto pack_write = [&](float (&a8)[8], float (&b8a)[8], float (&b8b)[8]) {
        int4 hi, lo;
        pack8(a8, hi, lo);
        *(int4*)(lds + awb)          = hi;   // A_hi @0
        *(int4*)(lds + 5120 + awb)   = lo;   // A_lo @5120
        pack8(b8a, hi, lo);
        *(int4*)(lds + 10240 + bwb0) = hi;   // B_hi @10240
        *(int4*)(lds + 20480 + bwb0) = lo;   // B_lo @20480
        pack8(b8b, hi, lo);
        *(int4*)(lds + 10240 + bwb1) = hi;
        *(int4*)(lds + 20480 + bwb1) = lo;
    };

    auto frag_mfma = [&]() {
        short8 ah[2], al[2];
        #pragma unroll
        for (int mf = 0; mf < 2; ++mf) {
            ah[mf] = *(const short8*)(lds + aoffs[mf]);
            al[mf] = *(const short8*)(lds + 5120 + aoffs[mf]);
        }
        #pragma unroll
        for (int nf = 0; nf < 4; ++nf) {
            const short8 bh = *(const short8*)(lds + boffs[nf]);
            const short8 bl = *(const short8*)(lds + 10240 + boffs[nf]);
            #pragma unroll
            for (int mf = 0; mf < 2; ++mf) {
                acc[mf][nf] = __builtin_amdgcn_mfma_f32_16x16x32_bf16(ah[mf], bh, acc[mf][nf], 0, 0, 0);
                acc[mf][nf] = __builtin_amdgcn_mfma_f32_16x16x32_bf16(ah[mf], bl, acc[mf][nf], 0, 0, 0);
                acc[mf][nf] = __builtin_amdgcn_mfma_f32_16x16x32_bf16(al[mf], bh, acc[mf][nf], 0, 0, 0);
            }
        }
    };

    // ---- prologue: P=step0 staged; Q=step1 in regs ----
    load_regs(0, a8P, b8aP, b8bP);
    load_regs(1, a8Q, b8aQ, b8bQ);
    pack_write(a8P, b8aP, b8bP);
    __syncthreads();

    // ---- main loop: unroll 2, 2 barriers/step, 2-step load->use distance ----
    for (int st = 0; st < nst; st += 2) {
        if (st + 2 < nst) load_regs(st + 2, a8P, b8aP, b8bP);
        frag_mfma();                          // step st (from LDS)
        __syncthreads();
        pack_write(a8Q, b8aQ, b8bQ);          // publish st+1 (loaded 1.5 steps ago)
        __syncthreads();
        if (st + 3 < nst) load_regs(st + 3, a8Q, b8aQ, b8bQ);
        frag_mfma();                          // step st+1
        __syncthreads();
        if (st + 2 < nst) {
            pack_write(a8P, b8aP, b8bP);      // publish st+2
            __syncthreads();
        }
    }

    // ---- store partial C tile: slab[m*120 + n] ----
    float* slab = partials + (size_t)((ch * 2 + wh) * NB + b) * SLABSZ;
    #pragma unroll
    for (int mf = 0; mf < 2; ++mf) {
        const int mrow = mt * 64 + wm * 32 + mf * 16 + g * 4;
        #pragma unroll
        for (int nf = 0; nf < 4; ++nf) {
            const int n = wn * 64 + nf * 16 + r16;
            if (n < KD) {
                #pragma unroll
                for (int r = 0; r < 4; ++r) {
                    const int m = mrow + r;
                    if (m < NFD) slab[(size_t)m * KD + n] = acc[mf][nf][r];
                }
            }
        }
    }
}

// ---------------------------------------------------------------------------
// reduce (NCH=6)
// ---------------------------------------------------------------------------
__global__ __launch_bounds__(256) void reduce_k(
    const float* __restrict__ partials, float* __restrict__ fhat, float* __restrict__ ghat)
{
    const int id = blockIdx.x * 256 + threadIdx.x;
    if (id >= NFD * KD) return;
    const int wb = blockIdx.y;
    const int wh = wb >> 4;
    const int b  = wb & 15;

    const float* p = partials + (size_t)(wh * NB + b) * SLABSZ + id;
    const size_t chstride = (size_t)2 * NB * SLABSZ;

    float s = 0.f;
    #pragma unroll
    for (int c = 0; c < NCH; ++c) s += p[c * chstride];

    float* dst = (wh ? ghat : fhat) + (size_t)b * NFD * KD + id;
    *dst = s;
}

// ---------------------------------------------------------------------------
// Generic TN SGEMM 64x64 tile — used by gram (unchanged, passing).
// ---------------------------------------------------------------------------
__device__ __forceinline__ void gemm_tn_64x64(
    const float* __restrict__ A, const float* __restrict__ B, float* __restrict__ C,
    int V, int M, int N, int m0, int n0)
{
    __shared__ float As[16][64];
    __shared__ float Bs[16][64];

    const int tid = threadIdx.x;
    const int tx = tid & 15;
    const int ty = tid >> 4;
    const int sr = tid >> 4;
    const int sc = (tid & 15) << 2;

    float acc[4][4] = {{0.f,0.f,0.f,0.f},{0.f,0.f,0.f,0.f},
                       {0.f,0.f,0.f,0.f},{0.f,0.f,0.f,0.f}};

    for (int v0 = 0; v0 < V; v0 += 16) {
        const int v = v0 + sr;
        float4 av; av.x = av.y = av.z = av.w = 0.f;
        float4 bv; bv.x = bv.y = bv.z = bv.w = 0.f;
        if (v < V) {
            const float* Ar = A + (size_t)v * M;
            const int ca = m0 + sc;
            if (ca + 3 < M) {
                av = *(const float4*)(Ar + ca);
            } else {
                if (ca + 0 < M) av.x = Ar[ca + 0];
                if (ca + 1 < M) av.y = Ar[ca + 1];
                if (ca + 2 < M) av.z = Ar[ca + 2];
                if (ca + 3 < M) av.w = Ar[ca + 3];
            }
            const float* Br = B + (size_t)v * N;
            const int cb = n0 + sc;
            if (cb + 3 < N) {
                bv = *(const float4*)(Br + cb);
            } else {
                if (cb + 0 < N) bv.x = Br[cb + 0];
                if (cb + 1 < N) bv.y = Br[cb + 1];
                if (cb + 2 < N) bv.z = Br[cb + 2];
                if (cb + 3 < N) bv.w = Br[cb + 3];
            }
        }
        __syncthreads();
        *(float4*)&As[sr][sc] = av;
        *(float4*)&Bs[sr][sc] = bv;
        __syncthreads();

        #pragma unroll
        for (int kk = 0; kk < 16; ++kk) {
            const float4 a4 = *(const float4*)&As[kk][ty << 2];
            const float4 b4 = *(const float4*)&Bs[kk][tx << 2];
            const float a[4]  = {a4.x, a4.y, a4.z, a4.w};
            const float bb[4] = {b4.x, b4.y, b4.z, b4.w};
            #pragma unroll
            for (int i = 0; i < 4; ++i)
                #pragma unroll
                for (int j = 0; j < 4; ++j)
                    acc[i][j] = fmaf(a[i], bb[j], acc[i][j]);
        }
    }

    #pragma unroll
    for (int i = 0; i < 4; ++i) {
        const int m = m0 + (ty << 2) + i;
        if (m < M) {
            #pragma unroll
            for (int j = 0; j < 4; ++j) {
                const int n = n0 + (tx << 2) + j;
                if (n < N) C[(size_t)m * N + n] = acc[i][j];
            }
        }
    }
}

__global__ __launch_bounds__(256) void gram_kernel(
    const float* __restrict__ fhat, const float* __restrict__ ghat,
    float* __restrict__ ftf, float* __restrict__ gtg, float* __restrict__ ftg)
{
    const int b = blockIdx.z;
    const int which = blockIdx.y;
    const int m0 = (blockIdx.x & 1) * 64;
    const int n0 = (blockIdx.x >> 1) * 64;

    const float* F = fhat + (size_t)b * NFD * KD;
    const float* G = ghat + (size_t)b * NFD * KD;
    const float* A  = (which == 1) ? G : F;
    const float* Bp = (which == 0) ? F : G;
    float* C = ((which == 0) ? ftf : (which == 1) ? gtg : ftg) + (size_t)b * KD * KD;

    gemm_tn_64x64(A, Bp, C, NFD, KD, KD, m0, n0);
}

// ---------------------------------------------------------------------------
// solve v6 (unchanged, passing): 480-thread Gauss-Jordan, 60 named scalars,
// padded 20-float prow segments (bank-clean), R=4 row reuse.
// ---------------------------------------------------------------------------
__device__ __forceinline__ float ldval(const float* __restrict__ A, const float* __restrict__ B,
                                       int pair, int row, int col) {
    if (col < KD) return A[row * KD + col];
    const int l = col - KD;
    return pair ? B[l * KD + row] : B[row * KD + l];
}

#define FOR15(OP) OP(0) OP(1) OP(2) OP(3) OP(4) OP(5) OP(6) OP(7) OP(8) OP(9) \
                  OP(10) OP(11) OP(12) OP(13) OP(14)

__global__ __launch_bounds__(480, 1) void solve_kernel(
    const float* __restrict__ ftf, const float* __restrict__ gtg,
    const float* __restrict__ ftg, float* __restrict__ out)
{
    const int pair = blockIdx.x;
    const int b = blockIdx.y;
    const int tid = threadIdx.x;
    const int cg = tid & 15;
    const int rg = tid >> 4;
    const int cbase = cg * 15;
    const int r0 = rg * 4;
    const int seg = cg * 20;

    const float* Ag = ((pair == 0) ? ftf : gtg) + (size_t)b * KD * KD;
    const float* Bg = ftg + (size_t)b * KD * KD;

    __shared__ __align__(16) float prow[2][320];
    __shared__ __align__(16) float pcol[2][120];

    #define DECL(I) float w##I = ldval(Ag, Bg, pair, r0 + 0, cbase + (I)); \
                    float x##I = ldval(Ag, Bg, pair, r0 + 1, cbase + (I)); \
                    float y##I = ldval(Ag, Bg, pair, r0 + 2, cbase + (I)); \
                    float z##I = ldval(Ag, Bg, pair, r0 + 3, cbase + (I));
    FOR15(DECL)
    #undef DECL

    if (rg == 0) {
        #define PUB0(I) prow[0][seg + (I)] = w##I;
        FOR15(PUB0)
        #undef PUB0
    }
    if (cg == 0) *(float4*)&pcol[0][r0] = float4{w0, x0, y0, z0};
    __syncthreads();

    int jseg = 0, joff = 0;

    for (int j = 0; j < KD; ++j) {
        const int cur = j & 1;
        const int nxt = cur ^ 1;

        const float pinv = 1.0f / prow[cur][jseg * 20 + joff];
        const float4 f4 = *(const float4*)&pcol[cur][r0];

        const float4 q0 = *(const float4*)&prow[cur][seg + 0];
        const float4 q1 = *(const float4*)&prow[cur][seg + 4];
        const float4 q2 = *(const float4*)&prow[cur][seg + 8];
        const float4 q3 = *(const float4*)&prow[cur][seg + 12];
        const float p0 = q0.x, p1 = q0.y, p2 = q0.z, p3 = q0.w;
        const float p4 = q1.x, p5 = q1.y, p6 = q1.z, p7 = q1.w;
        const float p8 = q2.x, p9 = q2.y, p10 = q2.z, p11 = q2.w;
        const float p12 = q3.x, p13 = q3.y, p14 = q3.z;

        const float fw = f4.x * pinv, fx = f4.y * pinv;
        const float fy = f4.z * pinv, fz = f4.w * pinv;

        #define UPD(I) w##I = fmaf(-fw, p##I, w##I); x##I = fmaf(-fx, p##I, x##I); \
                       y##I = fmaf(-fy, p##I, y##I); z##I = fmaf(-fz, p##I, z##I);
        FOR15(UPD)
        #undef UPD

        if (rg == (j >> 2)) {
            #define FW(I) w##I = p##I * pinv;
            #define FX(I) x##I = p##I * pinv;
            #define FY(I) y##I = p##I * pinv;
            #define FZ(I) z##I = p##I * pinv;
            switch (j & 3) {
                case 0: FOR15(FW) break;
                case 1: FOR15(FX) break;
                case 2: FOR15(FY) break;
                default: FOR15(FZ) break;
            }
            #undef FW
            #undef FX
            #undef FY
            #undef FZ
        }

        const int j2 = j + 1;

        if (j2 < KD && rg == (j2 >> 2)) {
            #define PW(I) prow[nxt][seg + (I)] = w##I;
            #define PX(I) prow[nxt][seg + (I)] = x##I;
            #define PY(I) prow[nxt][seg + (I)] = y##I;
            #define PZ(I) prow[nxt][seg + (I)] = z##I;
            switch (j2 & 3) {
                case 0: FOR15(PW) break;
                case 1: FOR15(PX) break;
                case 2: FOR15(PY) break;
                default: FOR15(PZ) break;
            }
            #undef PW
            #undef PX
            #undef PY
            #undef PZ
        }

        joff++; if (joff == 15) { joff = 0; jseg++; }
        if (j2 < KD && cg == jseg) {
            #define PC(I) case I: *(float4*)&pcol[nxt][r0] = float4{w##I, x##I, y##I, z##I}; break;
            switch (joff) {
                FOR15(PC)
                default: break;
            }
            #undef PC
        }
        __syncthreads();
    }

    if (cg >= 8) {
        float* op = out + (size_t)pair * NB * KD * KD + (size_t)b * KD * KD;
        #define OUTW(I) { const int l = cbase + (I) - KD; \
                          *(float4*)&op[l * KD + r0] = float4{w##I, x##I, y##I, z##I}; }
        FOR15(OUTW)
        #undef OUTW
    }
}

// ---------------------------------------------------------------------------
extern "C" void kernel_launch(void* const* d_in, const int* in_sizes, int n_in,
                              void* d_out, int out_size, void* d_ws, size_t ws_size,
                              hipStream_t stream)
{
    const float* feat_x  = (const float*)d_in[0];
    const float* feat_y  = (const float*)d_in[1];
    const float* evecs_x = (const float*)d_in[2];
    const float* evecs_y = (const float*)d_in[3];
    float* out = (float*)d_out;

    // ws layout (floats): pad 64 | partials 6ch*2wh*16b slabs = 8,110,080 |
    // fhat/ghat 675,840 ea (total ~38.2 MB). ftf/gtg/ftg alias partials.
    float* ws       = (float*)d_ws;
    float* partials = ws + 64;
    float* fhat     = partials + (size_t)NCH * 2 * NB * SLABSZ;
    float* ghat     = fhat + (size_t)NB * NFD * KD;
    float* ftf      = ws + 64;                            // aliases partials
    float* gtg      = ftf + (size_t)NB * KD * KD;
    float* ftg      = gtg + (size_t)NB * KD * KD;

    proj_mfma <<<dim3(36, 2, NB), 256, 0, stream>>>(feat_x, feat_y, evecs_x, evecs_y, partials);
    reduce_k  <<<dim3(165, 32), 256, 0, stream>>>(partials, fhat, ghat);
    gram_kernel<<<dim3(4, 3, NB), 256, 0, stream>>>(fhat, ghat, ftf, gtg, ftg);
    solve_kernel<<<dim3(2, NB), 480, 0, stream>>>(ftf, gtg, ftg, out);
}

// Round 14
// 307.935 us; speedup vs baseline: 1.0040x; 1.0040x over previous
//
#include <hip/hip_runtime.h>
#include <hip/hip_bf16.h>

#define NB 16
#define VV 5000
#define NFD 352
#define KD 120
#define NCH 8
#define CHUNK 625
#define SLABSZ (352 * 120)

typedef __attribute__((ext_vector_type(8))) short short8;
typedef __attribute__((ext_vector_type(4))) float float4v;

__device__ __forceinline__ unsigned short bfb(float a) {
    return __builtin_bit_cast(unsigned short, __float2bfloat16(a));
}

// split fp32 -> bf16 hi + bf16 lo(residual), pack 8 of each into int4
__device__ __forceinline__ void pack8(const float* f, int4& hi, int4& lo) {
    unsigned short h[8], l[8];
    #pragma unroll
    for (int j = 0; j < 8; ++j) {
        const float a = f[j];
        const __hip_bfloat16 hb = __float2bfloat16(a);
        h[j] = __builtin_bit_cast(unsigned short, hb);
        l[j] = bfb(a - __bfloat162float(hb));
    }
    hi.x = h[0] | (h[1] << 16); hi.y = h[2] | (h[3] << 16);
    hi.z = h[4] | (h[5] << 16); hi.w = h[6] | (h[6+1] << 16);
    lo.x = l[0] | (l[1] << 16); lo.y = l[2] | (l[3] << 16);
    lo.z = l[4] | (l[5] << 16); lo.w = l[6] | (l[7] << 16);
}

// ---------------------------------------------------------------------------
// proj v8: F_hat[b,f,k] = sum_v feat[b,v,f]*evecs[b,v,k]
// v7 spilled (2nd staging set -> WRITE_SIZE 107MB scratch). v8 = v6b's
// single-staging-set schedule + v3's traffic-optimal tile:
//   tile 128m x 128n (120 live), BK=32 -> evecs read 3x not 6x
//   (logical traffic 687 -> 456 MB), LDS 40KB -> 3 blocks/CU = 12 waves
//   (v3 dbuf had only 8), launch_bounds(256,3) -> VGPR cap 170, no spill.
// LDS: A_hi[128 x 80B]@0 | A_lo@10240 | B_hi@20480 | B_lo@30720 (40960 B).
// 80B rows: bank-quad = (5*row+g) mod 8, bijective over row mod 8 -> all
// b128 ops 2-way max (free). 4 waves 2x2, wave tile 64x64, acc 4x4.
// NCH=8 chunks of 625 v (8*625=5000), 20 steps each, last step tail-guarded.
// grid (24,2,16) = 768 = 8 x 96, bijective XCD swizzle.
// ---------------------------------------------------------------------------
__global__ __launch_bounds__(256, 3) void proj_mfma(
    const float* __restrict__ fx, const float* __restrict__ fy,
    const float* __restrict__ ex, const float* __restrict__ ey,
    float* __restrict__ partials)
{
    const int t = threadIdx.x;

    // bijective XCD swizzle: 768 = 8 x 96
    int lin = blockIdx.x + 24 * (blockIdx.y + 2 * blockIdx.z);
    lin = (lin & 7) * 96 + (lin >> 3);
    const int xx   = lin % 24;
    const int rest = lin / 24;
    const int wh = rest & 1;
    const int b  = rest >> 1;
    const int mt = xx % 3;
    const int ch = xx / 3;

    const float* Ab = (wh ? fy : fx) + (size_t)b * VV * NFD;
    const float* Bb = (wh ? ey : ex) + (size_t)b * VV * KD;
    const int m0 = mt * 128;

    __shared__ __align__(16) unsigned char lds[40960];

    // ---- staging geometry: A and B each 512 units (row, k-octet), 2/thread ----
    const int sn  = t & 127;                 // row within tile
    const int so0 = (t >> 7) & 3;            // unit 0 octet: 0|1
    const int so1 = ((256 + t) >> 7) & 3;    // unit 1 octet: 2|3
    const float* aSrc = Ab + min(m0 + sn, NFD - 1);   // clamp; dup masked at C-write
    const float* bSrc = Bb + min(sn, KD - 1);
    const int wb0 = sn * 80 + so0 * 16;
    const int wb1 = sn * 80 + so1 * 16;

    // ---- wave geometry: 4 waves 2x2, wave tile 64(m) x 64(n) ----
    const int lane = t & 63;
    const int wid  = t >> 6;
    const int wm = wid >> 1, wn = wid & 1;
    const int r16 = lane & 15;
    const int g   = lane >> 4;

    int aoffs[4], boffs[4];
    #pragma unroll
    for (int mf = 0; mf < 4; ++mf)
        aoffs[mf] = (wm * 64 + mf * 16 + r16) * 80 + g * 16;
    #pragma unroll
    for (int nf = 0; nf < 4; ++nf)
        boffs[nf] = 20480 + (wn * 64 + nf * 16 + r16) * 80 + g * 16;

    float4v acc[4][4];
    #pragma unroll
    for (int mf = 0; mf < 4; ++mf)
        #pragma unroll
        for (int nf = 0; nf < 4; ++nf)
            acc[mf][nf] = float4v{0.f, 0.f, 0.f, 0.f};

    const int chv0 = ch * CHUNK;
    const int vb   = chv0 + CHUNK;           // exclusive live bound (8*625=5000)
    const int nst  = 20;                     // ceil(625/32)

    float a8a[8], a8b[8], b8a[8], b8b[8];    // ONE staging set (v7's 2nd set spilled)

    auto load_regs = [&](int st) {
        const int v0  = chv0 + st * 32;
        const int va0 = v0 + so0 * 8;
        const int va1 = v0 + so1 * 8;
        if (v0 + 32 <= vb) {
            #pragma unroll
            for (int j = 0; j < 8; ++j) a8a[j] = aSrc[(size_t)(va0 + j) * NFD];
            #pragma unroll
            for (int j = 0; j < 8; ++j) a8b[j] = aSrc[(size_t)(va1 + j) * NFD];
            #pragma unroll
            for (int j = 0; j < 8; ++j) b8a[j] = bSrc[(size_t)(va0 + j) * KD];
            #pragma unroll
            for (int j = 0; j < 8; ++j) b8b[j] = bSrc[(size_t)(va1 + j) * KD];
        } else {
            #pragma unroll
            for (int j = 0; j < 8; ++j) {
                float v = 0.f;
                if (va0 + j < vb) v = aSrc[(size_t)(va0 + j) * NFD];
                a8a[j] = v;
            }
            #pragma unroll
            for (int j = 0; j < 8; ++j) {
                float v = 0.f;
                if (va1 + j < vb) v = aSrc[(size_t)(va1 + j) * NFD];
                a8b[j] = v;
            }
            #pragma unroll
            for (int j = 0; j < 8; ++j) {
                float v = 0.f;
                if (va0 + j < vb) v = bSrc[(size_t)(va0 + j) * KD];
                b8a[j] = v;
            }
            #pragma unroll
            for (int j = 0; j < 8; ++j) {
                float v = 0.f;
                if (va1 + j < vb) v = bSrc[(size_t)(va1 + j) * KD];
                b8b[j] = v;
            }
        }
    };

    auto pack_write = [&]() {
        int4 hi, lo;
        pack8(a8a, hi, lo);
        *(int4*)(lds + wb0)          = hi;   // A_hi @0
        *(int4*)(lds + 10240 + wb0)  = lo;   // A_lo @10240
        pack8(a8b, hi, lo);
        *(int4*)(lds + wb1)          = hi;
        *(int4*)(lds + 10240 + wb1)  = lo;
        pack8(b8a, hi, lo);
        *(int4*)(lds + 20480 + wb0)  = hi;   // B_hi @20480
        *(int4*)(lds + 30720 + wb0)  = lo;   // B_lo @30720
        pack8(b8b, hi, lo);
        *(int4*)(lds + 20480 + wb1)  = hi;
        *(int4*)(lds + 30720 + wb1)  = lo;
    };

    auto frag_mfma = [&]() {
        short8 ah[4], al[4];
        #pragma unroll
        for (int mf = 0; mf < 4; ++mf) {
            ah[mf] = *(const short8*)(lds + aoffs[mf]);
            al[mf] = *(const short8*)(lds + 10240 + aoffs[mf]);
        }
        #pragma unroll
        for (int nf = 0; nf < 4; ++nf) {
            const short8 bh = *(const short8*)(lds + boffs[nf]);
            const short8 bl = *(const short8*)(lds + 10240 + boffs[nf]);
            #pragma unroll
            for (int mf = 0; mf < 4; ++mf) {
                acc[mf][nf] = __builtin_amdgcn_mfma_f32_16x16x32_bf16(ah[mf], bh, acc[mf][nf], 0, 0, 0);
                acc[mf][nf] = __builtin_amdgcn_mfma_f32_16x16x32_bf16(ah[mf], bl, acc[mf][nf], 0, 0, 0);
                acc[mf][nf] = __builtin_amdgcn_mfma_f32_16x16x32_bf16(al[mf], bh, acc[mf][nf], 0, 0, 0);
            }
        }
    };

    // ---- prologue ----
    load_regs(0);
    pack_write();
    __syncthreads();

    // ---- main loop: issue loads early, write late ----
    for (int st = 0; st < nst; ++st) {
        if (st + 1 < nst) load_regs(st + 1);   // HBM latency hides under MFMA
        frag_mfma();
        __syncthreads();
        if (st + 1 < nst) {
            pack_write();
            __syncthreads();
        }
    }

    // ---- store partial C tile: slab[m*120 + n] ----
    float* slab = partials + (size_t)((ch * 2 + wh) * NB + b) * SLABSZ;
    #pragma unroll
    for (int mf = 0; mf < 4; ++mf) {
        const int mrow = mt * 128 + wm * 64 + mf * 16 + g * 4;
        #pragma unroll
        for (int nf = 0; nf < 4; ++nf) {
            const int n = wn * 64 + nf * 16 + r16;
            if (n < KD) {
                #pragma unroll
                for (int r = 0; r < 4; ++r) {
                    const int m = mrow + r;
                    if (m < NFD) slab[(size_t)m * KD + n] = acc[mf][nf][r];
                }
            }
        }
    }
}

// ---------------------------------------------------------------------------
// reduce (NCH=8)
// ---------------------------------------------------------------------------
__global__ __launch_bounds__(256) void reduce_k(
    const float* __restrict__ partials, float* __restrict__ fhat, float* __restrict__ ghat)
{
    const int id = blockIdx.x * 256 + threadIdx.x;
    if (id >= NFD * KD) return;
    const int wb = blockIdx.y;
    const int wh = wb >> 4;
    const int b  = wb & 15;

    const float* p = partials + (size_t)(wh * NB + b) * SLABSZ + id;
    const size_t chstride = (size_t)2 * NB * SLABSZ;

    float s = 0.f;
    #pragma unroll
    for (int c = 0; c < NCH; ++c) s += p[c * chstride];

    float* dst = (wh ? ghat : fhat) + (size_t)b * NFD * KD + id;
    *dst = s;
}

// ---------------------------------------------------------------------------
// Generic TN SGEMM 64x64 tile — used by gram (unchanged, passing).
// ---------------------------------------------------------------------------
__device__ __forceinline__ void gemm_tn_64x64(
    const float* __restrict__ A, const float* __restrict__ B, float* __restrict__ C,
    int V, int M, int N, int m0, int n0)
{
    __shared__ float As[16][64];
    __shared__ float Bs[16][64];

    const int tid = threadIdx.x;
    const int tx = tid & 15;
    const int ty = tid >> 4;
    const int sr = tid >> 4;
    const int sc = (tid & 15) << 2;

    float acc[4][4] = {{0.f,0.f,0.f,0.f},{0.f,0.f,0.f,0.f},
                       {0.f,0.f,0.f,0.f},{0.f,0.f,0.f,0.f}};

    for (int v0 = 0; v0 < V; v0 += 16) {
        const int v = v0 + sr;
        float4 av; av.x = av.y = av.z = av.w = 0.f;
        float4 bv; bv.x = bv.y = bv.z = bv.w = 0.f;
        if (v < V) {
            const float* Ar = A + (size_t)v * M;
            const int ca = m0 + sc;
            if (ca + 3 < M) {
                av = *(const float4*)(Ar + ca);
            } else {
                if (ca + 0 < M) av.x = Ar[ca + 0];
                if (ca + 1 < M) av.y = Ar[ca + 1];
                if (ca + 2 < M) av.z = Ar[ca + 2];
                if (ca + 3 < M) av.w = Ar[ca + 3];
            }
            const float* Br = B + (size_t)v * N;
            const int cb = n0 + sc;
            if (cb + 3 < N) {
                bv = *(const float4*)(Br + cb);
            } else {
                if (cb + 0 < N) bv.x = Br[cb + 0];
                if (cb + 1 < N) bv.y = Br[cb + 1];
                if (cb + 2 < N) bv.z = Br[cb + 2];
                if (cb + 3 < N) bv.w = Br[cb + 3];
            }
        }
        __syncthreads();
        *(float4*)&As[sr][sc] = av;
        *(float4*)&Bs[sr][sc] = bv;
        __syncthreads();

        #pragma unroll
        for (int kk = 0; kk < 16; ++kk) {
            const float4 a4 = *(const float4*)&As[kk][ty << 2];
            const float4 b4 = *(const float4*)&Bs[kk][tx << 2];
            const float a[4]  = {a4.x, a4.y, a4.z, a4.w};
            const float bb[4] = {b4.x, b4.y, b4.z, b4.w};
            #pragma unroll
            for (int i = 0; i < 4; ++i)
                #pragma unroll
                for (int j = 0; j < 4; ++j)
                    acc[i][j] = fmaf(a[i], bb[j], acc[i][j]);
        }
    }

    #pragma unroll
    for (int i = 0; i < 4; ++i) {
        const int m = m0 + (ty << 2) + i;
        if (m < M) {
            #pragma unroll
            for (int j = 0; j < 4; ++j) {
                const int n = n0 + (tx << 2) + j;
                if (n < N) C[(size_t)m * N + n] = acc[i][j];
            }
        }
    }
}

__global__ __launch_bounds__(256) void gram_kernel(
    const float* __restrict__ fhat, const float* __restrict__ ghat,
    float* __restrict__ ftf, float* __restrict__ gtg, float* __restrict__ ftg)
{
    const int b = blockIdx.z;
    const int which = blockIdx.y;
    const int m0 = (blockIdx.x & 1) * 64;
    const int n0 = (blockIdx.x >> 1) * 64;

    const float* F = fhat + (size_t)b * NFD * KD;
    const float* G = ghat + (size_t)b * NFD * KD;
    const float* A  = (which == 1) ? G : F;
    const float* Bp = (which == 0) ? F : G;
    float* C = ((which == 0) ? ftf : (which == 1) ? gtg : ftg) + (size_t)b * KD * KD;

    gemm_tn_64x64(A, Bp, C, NFD, KD, KD, m0, n0);
}

// ---------------------------------------------------------------------------
// solve v6 (unchanged, passing): 480-thread Gauss-Jordan, 60 named scalars,
// padded 20-float prow segments (bank-clean), R=4 row reuse.
// ---------------------------------------------------------------------------
__device__ __forceinline__ float ldval(const float* __restrict__ A, const float* __restrict__ B,
                                       int pair, int row, int col) {
    if (col < KD) return A[row * KD + col];
    const int l = col - KD;
    return pair ? B[l * KD + row] : B[row * KD + l];
}

#define FOR15(OP) OP(0) OP(1) OP(2) OP(3) OP(4) OP(5) OP(6) OP(7) OP(8) OP(9) \
                  OP(10) OP(11) OP(12) OP(13) OP(14)

__global__ __launch_bounds__(480, 1) void solve_kernel(
    const float* __restrict__ ftf, const float* __restrict__ gtg,
    const float* __restrict__ ftg, float* __restrict__ out)
{
    const int pair = blockIdx.x;
    const int b = blockIdx.y;
    const int tid = threadIdx.x;
    const int cg = tid & 15;
    const int rg = tid >> 4;
    const int cbase = cg * 15;
    const int r0 = rg * 4;
    const int seg = cg * 20;

    const float* Ag = ((pair == 0) ? ftf : gtg) + (size_t)b * KD * KD;
    const float* Bg = ftg + (size_t)b * KD * KD;

    __shared__ __align__(16) float prow[2][320];
    __shared__ __align__(16) float pcol[2][120];

    #define DECL(I) float w##I = ldval(Ag, Bg, pair, r0 + 0, cbase + (I)); \
                    float x##I = ldval(Ag, Bg, pair, r0 + 1, cbase + (I)); \
                    float y##I = ldval(Ag, Bg, pair, r0 + 2, cbase + (I)); \
                    float z##I = ldval(Ag, Bg, pair, r0 + 3, cbase + (I));
    FOR15(DECL)
    #undef DECL

    if (rg == 0) {
        #define PUB0(I) prow[0][seg + (I)] = w##I;
        FOR15(PUB0)
        #undef PUB0
    }
    if (cg == 0) *(float4*)&pcol[0][r0] = float4{w0, x0, y0, z0};
    __syncthreads();

    int jseg = 0, joff = 0;

    for (int j = 0; j < KD; ++j) {
        const int cur = j & 1;
        const int nxt = cur ^ 1;

        const float pinv = 1.0f / prow[cur][jseg * 20 + joff];
        const float4 f4 = *(const float4*)&pcol[cur][r0];

        const float4 q0 = *(const float4*)&prow[cur][seg + 0];
        const float4 q1 = *(const float4*)&prow[cur][seg + 4];
        const float4 q2 = *(const float4*)&prow[cur][seg + 8];
        const float4 q3 = *(const float4*)&prow[cur][seg + 12];
        const float p0 = q0.x, p1 = q0.y, p2 = q0.z, p3 = q0.w;
        const float p4 = q1.x, p5 = q1.y, p6 = q1.z, p7 = q1.w;
        const float p8 = q2.x, p9 = q2.y, p10 = q2.z, p11 = q2.w;
        const float p12 = q3.x, p13 = q3.y, p14 = q3.z;

        const float fw = f4.x * pinv, fx = f4.y * pinv;
        const float fy = f4.z * pinv, fz = f4.w * pinv;

        #define UPD(I) w##I = fmaf(-fw, p##I, w##I); x##I = fmaf(-fx, p##I, x##I); \
                       y##I = fmaf(-fy, p##I, y##I); z##I = fmaf(-fz, p##I, z##I);
        FOR15(UPD)
        #undef UPD

        if (rg == (j >> 2)) {
            #define FW(I) w##I = p##I * pinv;
            #define FX(I) x##I = p##I * pinv;
            #define FY(I) y##I = p##I * pinv;
            #define FZ(I) z##I = p##I * pinv;
            switch (j & 3) {
                case 0: FOR15(FW) break;
                case 1: FOR15(FX) break;
                case 2: FOR15(FY) break;
                default: FOR15(FZ) break;
            }
            #undef FW
            #undef FX
            #undef FY
            #undef FZ
        }

        const int j2 = j + 1;

        if (j2 < KD && rg == (j2 >> 2)) {
            #define PW(I) prow[nxt][seg + (I)] = w##I;
            #define PX(I) prow[nxt][seg + (I)] = x##I;
            #define PY(I) prow[nxt][seg + (I)] = y##I;
            #define PZ(I) prow[nxt][seg + (I)] = z##I;
            switch (j2 & 3) {
                case 0: FOR15(PW) break;
                case 1: FOR15(PX) break;
                case 2: FOR15(PY) break;
                default: FOR15(PZ) break;
            }
            #undef PW
            #undef PX
            #undef PY
            #undef PZ
        }

        joff++; if (joff == 15) { joff = 0; jseg++; }
        if (j2 < KD && cg == jseg) {
            #define PC(I) case I: *(float4*)&pcol[nxt][r0] = float4{w##I, x##I, y##I, z##I}; break;
            switch (joff) {
                FOR15(PC)
                default: break;
            }
            #undef PC
        }
        __syncthreads();
    }

    if (cg >= 8) {
        float* op = out + (size_t)pair * NB * KD * KD + (size_t)b * KD * KD;
        #define OUTW(I) { const int l = cbase + (I) - KD; \
                          *(float4*)&op[l * KD + r0] = float4{w##I, x##I, y##I, z##I}; }
        FOR15(OUTW)
        #undef OUTW
    }
}

// ---------------------------------------------------------------------------
extern "C" void kernel_launch(void* const* d_in, const int* in_sizes, int n_in,
                              void* d_out, int out_size, void* d_ws, size_t ws_size,
                              hipStream_t stream)
{
    const float* feat_x  = (const float*)d_in[0];
    const float* feat_y  = (const float*)d_in[1];
    const float* evecs_x = (const float*)d_in[2];
    const float* evecs_y = (const float*)d_in[3];
    float* out = (float*)d_out;

    // ws layout (floats): pad 64 | partials 8ch*2wh*16b slabs = 10,813,440 |
    // fhat/ghat 675,840 ea (total ~48.7 MB). ftf/gtg/ftg alias partials.
    float* ws       = (float*)d_ws;
    float* partials = ws + 64;
    float* fhat     = partials + (size_t)NCH * 2 * NB * SLABSZ;
    float* ghat     = fhat + (size_t)NB * NFD * KD;
    float* ftf      = ws + 64;                            // aliases partials
    float* gtg      = ftf + (size_t)NB * KD * KD;
    float* ftg      = gtg + (size_t)NB * KD * KD;

    proj_mfma <<<dim3(24, 2, NB), 256, 0, stream>>>(feat_x, feat_y, evecs_x, evecs_y, partials);
    reduce_k  <<<dim3(165, 32), 256, 0, stream>>>(partials, fhat, ghat);
    gram_kernel<<<dim3(4, 3, NB), 256, 0, stream>>>(fhat, ghat, ftf, gtg, ftg);
    solve_kernel<<<dim3(2, NB), 480, 0, stream>>>(ftf, gtg, ftg, out);
}

// Round 15
// 208.880 us; speedup vs baseline: 1.4801x; 1.4742x over previous
//
#include <hip/hip_runtime.h>
#include <hip/hip_bf16.h>

#define NB 16
#define VV 5000
#define NFD 352
#define KD 120
#define NCH 5
#define SLABSZ (352 * 120)

typedef __attribute__((ext_vector_type(8))) short short8;
typedef __attribute__((ext_vector_type(4))) float float4v;

__device__ __forceinline__ unsigned short bfb(float a) {
    return __builtin_bit_cast(unsigned short, __float2bfloat16(a));
}

// split fp32 -> bf16 hi + bf16 lo(residual), pack 8 of each into int4
__device__ __forceinline__ void pack8(const float* f, int4& hi, int4& lo) {
    unsigned short h[8], l[8];
    #pragma unroll
    for (int j = 0; j < 8; ++j) {
        const float a = f[j];
        const __hip_bfloat16 hb = __float2bfloat16(a);
        h[j] = __builtin_bit_cast(unsigned short, hb);
        l[j] = bfb(a - __bfloat162float(hb));
    }
    hi.x = h[0] | (h[1] << 16); hi.y = h[2] | (h[3] << 16);
    hi.z = h[4] | (h[5] << 16); hi.w = h[6] | (h[7] << 16);
    lo.x = l[0] | (l[1] << 16); lo.y = l[2] | (l[3] << 16);
    lo.z = l[4] | (l[5] << 16); lo.w = l[6] | (l[7] << 16);
}

// ---------------------------------------------------------------------------
// proj v3 (RESTORED round-8 state — empirical best: proj ~120us, total 208.8us):
// BK=32, double-buffered LDS ping-pong (2 x 32KB), 2-deep register prefetch
// (P/Q named sets), ONE barrier per step: loads(st+2) || compute(st) ||
// pack+write(st+1 -> other buf).
// LDS per plane: (m,k-octet o) at m*64 + ((o ^ ((m>>1)&3))*16) — write b128
// and read b128 both bank-conflict-free. Planes: A_hi 0 | A_lo 8K | B_hi 16K
// | B_lo 24K; +32K for the second buffer. Tile 128x128, 4 waves 2x2.
// XCD swizzle (480 = 8*60, bijective).
// v4(no-LDS)/v5(fp32-LDS)/v6b(80B-pad)/v7(2nd staging set)/v8(128m 3-blk)
// all measured WORSE (spill or LDS-issue or latency) — see session journal.
// ---------------------------------------------------------------------------
__global__ __launch_bounds__(256, 2) void proj_mfma(
    const float* __restrict__ fx, const float* __restrict__ fy,
    const float* __restrict__ ex, const float* __restrict__ ey,
    float* __restrict__ partials)
{
    const int t = threadIdx.x;

    // ---- bijective XCD-chunk swizzle: 480 blocks = 8 XCDs x 60 ----
    int lin = blockIdx.x + 15 * (blockIdx.y + 2 * blockIdx.z);
    lin = (lin & 7) * 60 + (lin >> 3);
    const int xx   = lin % 15;
    const int rest = lin / 15;
    const int wh = rest & 1;
    const int b  = rest >> 1;
    const int mt = xx % 3;
    const int ch = xx / 3;

    const float* Ab = (wh ? fy : fx) + (size_t)b * VV * NFD;
    const float* Bb = (wh ? ey : ex) + (size_t)b * VV * KD;
    const int m0 = mt * 128;

    __shared__ int4 smem4[4096];                 // 64 KB = 2 x 32KB buffers
    unsigned char* smem = (unsigned char*)smem4;

    // ---- staging precompute: 2 A units + 2 B units (m, k-octet) ----
    int acol[2], awb[2], ao[2];
    #pragma unroll
    for (int i = 0; i < 2; ++i) {
        const int q = i * 256 + t;               // 0..511
        const int m = q & 127;
        const int o = q >> 7;                    // k-octet 0..3
        acol[i] = min(m0 + m, NFD - 1);          // clamp: dup cols never stored to C
        awb[i]  = m * 64 + ((o ^ ((m >> 1) & 3)) * 16);
        ao[i]   = o;
    }
    int bcol[2], bwb[2], bo[2];
    #pragma unroll
    for (int i = 0; i < 2; ++i) {
        const int q = i * 256 + t;
        const int n = q & 127;
        const int o = q >> 7;
        bcol[i] = min(n, KD - 1);
        bwb[i]  = n * 64 + ((o ^ ((n >> 1) & 3)) * 16);
        bo[i]   = o;
    }

    // ---- wave geometry: 4 waves as 2x2, wave tile 64x64 ----
    const int lane = t & 63;
    const int wid  = t >> 6;
    const int wm = wid >> 1, wn = wid & 1;
    const int r16 = lane & 15;
    const int g   = lane >> 4;

    int abase[4], bbase[4];
    #pragma unroll
    for (int mf = 0; mf < 4; ++mf) {
        const int m = wm * 64 + mf * 16 + r16;
        abase[mf] = m * 64 + ((g ^ ((m >> 1) & 3)) * 16);
    }
    #pragma unroll
    for (int nf = 0; nf < 4; ++nf) {
        const int n = wn * 64 + nf * 16 + r16;
        bbase[nf] = n * 64 + ((g ^ ((n >> 1) & 3)) * 16);
    }

    float4v acc[4][4];
    #pragma unroll
    for (int mf = 0; mf < 4; ++mf)
        #pragma unroll
        for (int nf = 0; nf < 4; ++nf)
            acc[mf][nf] = float4v{0.f, 0.f, 0.f, 0.f};

    const int step0 = ch * 32;                   // V-steps of 32
    const int nst   = (ch < 4) ? 32 : 30;        // 4*32+30 = 158 steps >= 5000/32

    float faP[2][8], fbP[2][8], faQ[2][8], fbQ[2][8];

    auto do_loads = [&](int st, float (&fa)[2][8], float (&fb)[2][8]) {
        const int v0 = (step0 + st) * 32;
        if (v0 + 32 <= VV) {
            #pragma unroll
            for (int i = 0; i < 2; ++i) {
                const float* pa = Ab + (size_t)(v0 + ao[i] * 8) * NFD + acol[i];
                #pragma unroll
                for (int j = 0; j < 8; ++j) fa[i][j] = pa[j * NFD];
            }
            #pragma unroll
            for (int i = 0; i < 2; ++i) {
                const float* pb = Bb + (size_t)(v0 + bo[i] * 8) * KD + bcol[i];
                #pragma unroll
                for (int j = 0; j < 8; ++j) fb[i][j] = pb[j * KD];
            }
        } else {
            #pragma unroll
            for (int i = 0; i < 2; ++i) {
                const float* pa = Ab + (size_t)(v0 + ao[i] * 8) * NFD + acol[i];
                #pragma unroll
                for (int j = 0; j < 8; ++j) {
                    const int v = v0 + ao[i] * 8 + j;
                    fa[i][j] = (v < VV) ? pa[j * NFD] : 0.f;
                }
            }
            #pragma unroll
            for (int i = 0; i < 2; ++i) {
                const float* pb = Bb + (size_t)(v0 + bo[i] * 8) * KD + bcol[i];
                #pragma unroll
                for (int j = 0; j < 8; ++j) {
                    const int v = v0 + bo[i] * 8 + j;
                    fb[i][j] = (v < VV) ? pb[j * KD] : 0.f;
                }
            }
        }
    };

    auto do_writes = [&](int bufb, float (&fa)[2][8], float (&fb)[2][8]) {
        #pragma unroll
        for (int i = 0; i < 2; ++i) {
            int4 hi, lo;
            pack8(fa[i], hi, lo);
            *(int4*)(smem + bufb + awb[i])        = hi;
            *(int4*)(smem + bufb + awb[i] + 8192) = lo;
        }
        #pragma unroll
        for (int i = 0; i < 2; ++i) {
            int4 hi, lo;
            pack8(fb[i], hi, lo);
            *(int4*)(smem + bufb + 16384 + bwb[i]) = hi;
            *(int4*)(smem + bufb + 24576 + bwb[i]) = lo;
        }
    };

    auto compute = [&](int bufb) {
        short8 ah[4], al[4], bh[4], bl[4];
        #pragma unroll
        for (int mf = 0; mf < 4; ++mf) {
            ah[mf] = *(const short8*)(smem + bufb + abase[mf]);
            al[mf] = *(const short8*)(smem + bufb + abase[mf] + 8192);
        }
        #pragma unroll
        for (int nf = 0; nf < 4; ++nf) {
            bh[nf] = *(const short8*)(smem + bufb + 16384 + bbase[nf]);
            bl[nf] = *(const short8*)(smem + bufb + 24576 + bbase[nf]);
        }
        #pragma unroll
        for (int mf = 0; mf < 4; ++mf)
            #pragma unroll
            for (int nf = 0; nf < 4; ++nf) {
                acc[mf][nf] = __builtin_amdgcn_mfma_f32_16x16x32_bf16(ah[mf], bh[nf], acc[mf][nf], 0, 0, 0);
                acc[mf][nf] = __builtin_amdgcn_mfma_f32_16x16x32_bf16(ah[mf], bl[nf], acc[mf][nf], 0, 0, 0);
                acc[mf][nf] = __builtin_amdgcn_mfma_f32_16x16x32_bf16(al[mf], bh[nf], acc[mf][nf], 0, 0, 0);
            }
    };

    // ---- prologue: prefetch steps 0,1; publish step 0 into buf0 ----
    do_loads(0, faP, fbP);
    do_loads(1, faQ, fbQ);
    do_writes(0, faP, fbP);
    __syncthreads();

    // ---- main loop: 2 steps per iteration, 1 barrier per step ----
    for (int i = 0; i < nst / 2; ++i) {
        const int st = 2 * i;
        // even step: compute buf0; stage st+1 into buf1; prefetch st+2
        if (st + 2 < nst) do_loads(st + 2, faP, fbP);
        compute(0);
        do_writes(32768, faQ, fbQ);          // st+1 (always < nst: nst even)
        __syncthreads();
        // odd step: compute buf1; stage st+2 into buf0; prefetch st+3
        if (st + 3 < nst) do_loads(st + 3, faQ, fbQ);
        compute(32768);
        if (st + 2 < nst) do_writes(0, faP, fbP);
        __syncthreads();
    }

    // ---- store partial C tile: slab[m*120 + n] ----
    float* slab = partials + (size_t)((ch * 2 + wh) * NB + b) * SLABSZ;
    #pragma unroll
    for (int mf = 0; mf < 4; ++mf) {
        const int mrow = mt * 128 + wm * 64 + mf * 16 + g * 4;
        #pragma unroll
        for (int nf = 0; nf < 4; ++nf) {
            const int n = wn * 64 + nf * 16 + r16;
            if (n < KD) {
                #pragma unroll
                for (int r = 0; r < 4; ++r) {
                    const int m = mrow + r;
                    if (m < NFD) slab[(size_t)m * KD + n] = acc[mf][nf][r];
                }
            }
        }
    }
}

// ---------------------------------------------------------------------------
// reduce (NCH=5)
// ---------------------------------------------------------------------------
__global__ __launch_bounds__(256) void reduce_k(
    const float* __restrict__ partials, float* __restrict__ fhat, float* __restrict__ ghat)
{
    const int id = blockIdx.x * 256 + threadIdx.x;
    if (id >= NFD * KD) return;
    const int wb = blockIdx.y;
    const int wh = wb >> 4;
    const int b  = wb & 15;

    const float* p = partials + (size_t)(wh * NB + b) * SLABSZ + id;
    const size_t chstride = (size_t)2 * NB * SLABSZ;

    float s = 0.f;
    #pragma unroll
    for (int c = 0; c < NCH; ++c) s += p[c * chstride];

    float* dst = (wh ? ghat : fhat) + (size_t)b * NFD * KD + id;
    *dst = s;
}

// ---------------------------------------------------------------------------
// Generic TN SGEMM 64x64 tile — used by gram (unchanged, passing).
// ---------------------------------------------------------------------------
__device__ __forceinline__ void gemm_tn_64x64(
    const float* __restrict__ A, const float* __restrict__ B, float* __restrict__ C,
    int V, int M, int N, int m0, int n0)
{
    __shared__ float As[16][64];
    __shared__ float Bs[16][64];

    const int tid = threadIdx.x;
    const int tx = tid & 15;
    const int ty = tid >> 4;
    const int sr = tid >> 4;
    const int sc = (tid & 15) << 2;

    float acc[4][4] = {{0.f,0.f,0.f,0.f},{0.f,0.f,0.f,0.f},
                       {0.f,0.f,0.f,0.f},{0.f,0.f,0.f,0.f}};

    for (int v0 = 0; v0 < V; v0 += 16) {
        const int v = v0 + sr;
        float4 av; av.x = av.y = av.z = av.w = 0.f;
        float4 bv; bv.x = bv.y = bv.z = bv.w = 0.f;
        if (v < V) {
            const float* Ar = A + (size_t)v * M;
            const int ca = m0 + sc;
            if (ca + 3 < M) {
                av = *(const float4*)(Ar + ca);
            } else {
                if (ca + 0 < M) av.x = Ar[ca + 0];
                if (ca + 1 < M) av.y = Ar[ca + 1];
                if (ca + 2 < M) av.z = Ar[ca + 2];
                if (ca + 3 < M) av.w = Ar[ca + 3];
            }
            const float* Br = B + (size_t)v * N;
            const int cb = n0 + sc;
            if (cb + 3 < N) {
                bv = *(const float4*)(Br + cb);
            } else {
                if (cb + 0 < N) bv.x = Br[cb + 0];
                if (cb + 1 < N) bv.y = Br[cb + 1];
                if (cb + 2 < N) bv.z = Br[cb + 2];
                if (cb + 3 < N) bv.w = Br[cb + 3];
            }
        }
        __syncthreads();
        *(float4*)&As[sr][sc] = av;
        *(float4*)&Bs[sr][sc] = bv;
        __syncthreads();

        #pragma unroll
        for (int kk = 0; kk < 16; ++kk) {
            const float4 a4 = *(const float4*)&As[kk][ty << 2];
            const float4 b4 = *(const float4*)&Bs[kk][tx << 2];
            const float a[4]  = {a4.x, a4.y, a4.z, a4.w};
            const float bb[4] = {b4.x, b4.y, b4.z, b4.w};
            #pragma unroll
            for (int i = 0; i < 4; ++i)
                #pragma unroll
                for (int j = 0; j < 4; ++j)
                    acc[i][j] = fmaf(a[i], bb[j], acc[i][j]);
        }
    }

    #pragma unroll
    for (int i = 0; i < 4; ++i) {
        const int m = m0 + (ty << 2) + i;
        if (m < M) {
            #pragma unroll
            for (int j = 0; j < 4; ++j) {
                const int n = n0 + (tx << 2) + j;
                if (n < N) C[(size_t)m * N + n] = acc[i][j];
            }
        }
    }
}

__global__ __launch_bounds__(256) void gram_kernel(
    const float* __restrict__ fhat, const float* __restrict__ ghat,
    float* __restrict__ ftf, float* __restrict__ gtg, float* __restrict__ ftg)
{
    const int b = blockIdx.z;
    const int which = blockIdx.y;
    const int m0 = (blockIdx.x & 1) * 64;
    const int n0 = (blockIdx.x >> 1) * 64;

    const float* F = fhat + (size_t)b * NFD * KD;
    const float* G = ghat + (size_t)b * NFD * KD;
    const float* A  = (which == 1) ? G : F;
    const float* Bp = (which == 0) ? F : G;
    float* C = ((which == 0) ? ftf : (which == 1) ? gtg : ftg) + (size_t)b * KD * KD;

    gemm_tn_64x64(A, Bp, C, NFD, KD, KD, m0, n0);
}

// ---------------------------------------------------------------------------
// solve v6 (unchanged, passing): 480-thread Gauss-Jordan, 60 named scalars,
// padded 20-float prow segments (bank-clean), R=4 row reuse.
// ---------------------------------------------------------------------------
__device__ __forceinline__ float ldval(const float* __restrict__ A, const float* __restrict__ B,
                                       int pair, int row, int col) {
    if (col < KD) return A[row * KD + col];
    const int l = col - KD;
    return pair ? B[l * KD + row] : B[row * KD + l];
}

#define FOR15(OP) OP(0) OP(1) OP(2) OP(3) OP(4) OP(5) OP(6) OP(7) OP(8) OP(9) \
                  OP(10) OP(11) OP(12) OP(13) OP(14)

__global__ __launch_bounds__(480, 1) void solve_kernel(
    const float* __restrict__ ftf, const float* __restrict__ gtg,
    const float* __restrict__ ftg, float* __restrict__ out)
{
    const int pair = blockIdx.x;
    const int b = blockIdx.y;
    const int tid = threadIdx.x;
    const int cg = tid & 15;
    const int rg = tid >> 4;
    const int cbase = cg * 15;
    const int r0 = rg * 4;
    const int seg = cg * 20;

    const float* Ag = ((pair == 0) ? ftf : gtg) + (size_t)b * KD * KD;
    const float* Bg = ftg + (size_t)b * KD * KD;

    __shared__ __align__(16) float prow[2][320];
    __shared__ __align__(16) float pcol[2][120];

    #define DECL(I) float w##I = ldval(Ag, Bg, pair, r0 + 0, cbase + (I)); \
                    float x##I = ldval(Ag, Bg, pair, r0 + 1, cbase + (I)); \
                    float y##I = ldval(Ag, Bg, pair, r0 + 2, cbase + (I)); \
                    float z##I = ldval(Ag, Bg, pair, r0 + 3, cbase + (I));
    FOR15(DECL)
    #undef DECL

    if (rg == 0) {
        #define PUB0(I) prow[0][seg + (I)] = w##I;
        FOR15(PUB0)
        #undef PUB0
    }
    if (cg == 0) *(float4*)&pcol[0][r0] = float4{w0, x0, y0, z0};
    __syncthreads();

    int jseg = 0, joff = 0;

    for (int j = 0; j < KD; ++j) {
        const int cur = j & 1;
        const int nxt = cur ^ 1;

        const float pinv = 1.0f / prow[cur][jseg * 20 + joff];
        const float4 f4 = *(const float4*)&pcol[cur][r0];

        const float4 q0 = *(const float4*)&prow[cur][seg + 0];
        const float4 q1 = *(const float4*)&prow[cur][seg + 4];
        const float4 q2 = *(const float4*)&prow[cur][seg + 8];
        const float4 q3 = *(const float4*)&prow[cur][seg + 12];
        const float p0 = q0.x, p1 = q0.y, p2 = q0.z, p3 = q0.w;
        const float p4 = q1.x, p5 = q1.y, p6 = q1.z, p7 = q1.w;
        const float p8 = q2.x, p9 = q2.y, p10 = q2.z, p11 = q2.w;
        const float p12 = q3.x, p13 = q3.y, p14 = q3.z;

        const float fw = f4.x * pinv, fx = f4.y * pinv;
        const float fy = f4.z * pinv, fz = f4.w * pinv;

        #define UPD(I) w##I = fmaf(-fw, p##I, w##I); x##I = fmaf(-fx, p##I, x##I); \
                       y##I = fmaf(-fy, p##I, y##I); z##I = fmaf(-fz, p##I, z##I);
        FOR15(UPD)
        #undef UPD

        if (rg == (j >> 2)) {
            #define FW(I) w##I = p##I * pinv;
            #define FX(I) x##I = p##I * pinv;
            #define FY(I) y##I = p##I * pinv;
            #define FZ(I) z##I = p##I * pinv;
            switch (j & 3) {
                case 0: FOR15(FW) break;
                case 1: FOR15(FX) break;
                case 2: FOR15(FY) break;
                default: FOR15(FZ) break;
            }
            #undef FW
            #undef FX
            #undef FY
            #undef FZ
        }

        const int j2 = j + 1;

        if (j2 < KD && rg == (j2 >> 2)) {
            #define PW(I) prow[nxt][seg + (I)] = w##I;
            #define PX(I) prow[nxt][seg + (I)] = x##I;
            #define PY(I) prow[nxt][seg + (I)] = y##I;
            #define PZ(I) prow[nxt][seg + (I)] = z##I;
            switch (j2 & 3) {
                case 0: FOR15(PW) break;
                case 1: FOR15(PX) break;
                case 2: FOR15(PY) break;
                default: FOR15(PZ) break;
            }
            #undef PW
            #undef PX
            #undef PY
            #undef PZ
        }

        joff++; if (joff == 15) { joff = 0; jseg++; }
        if (j2 < KD && cg == jseg) {
            #define PC(I) case I: *(float4*)&pcol[nxt][r0] = float4{w##I, x##I, y##I, z##I}; break;
            switch (joff) {
                FOR15(PC)
                default: break;
            }
            #undef PC
        }
        __syncthreads();
    }

    if (cg >= 8) {
        float* op = out + (size_t)pair * NB * KD * KD + (size_t)b * KD * KD;
        #define OUTW(I) { const int l = cbase + (I) - KD; \
                          *(float4*)&op[l * KD + r0] = float4{w##I, x##I, y##I, z##I}; }
        FOR15(OUTW)
        #undef OUTW
    }
}

// ---------------------------------------------------------------------------
extern "C" void kernel_launch(void* const* d_in, const int* in_sizes, int n_in,
                              void* d_out, int out_size, void* d_ws, size_t ws_size,
                              hipStream_t stream)
{
    const float* feat_x  = (const float*)d_in[0];
    const float* feat_y  = (const float*)d_in[1];
    const float* evecs_x = (const float*)d_in[2];
    const float* evecs_y = (const float*)d_in[3];
    float* out = (float*)d_out;

    // ws layout (floats): partials NCH*2*NB slabs of 352*120 = 6,758,400 |
    // fhat/ghat 675,840 ea. ftf/gtg/ftg alias partials (dead after reduce_k).
    float* ws       = (float*)d_ws;
    float* partials = ws;
    float* fhat     = partials + (size_t)NCH * 2 * NB * SLABSZ;
    float* ghat     = fhat + (size_t)NB * NFD * KD;
    float* ftf      = ws;                                 // aliases partials
    float* gtg      = ftf + (size_t)NB * KD * KD;
    float* ftg      = gtg + (size_t)NB * KD * KD;

    proj_mfma <<<dim3(15, 2, NB), 256, 0, stream>>>(feat_x, feat_y, evecs_x, evecs_y, partials);
    reduce_k  <<<dim3(165, 32), 256, 0, stream>>>(partials, fhat, ghat);
    gram_kernel<<<dim3(4, 3, NB), 256, 0, stream>>>(fhat, ghat, ftf, gtg, ftg);
    solve_kernel<<<dim3(2, NB), 480, 0, stream>>>(ftf, gtg, ftg, out);
}